// Round 7
// baseline (378.339 us; speedup 1.0000x reference)
//
#include <hip/hip_runtime.h>
#include <cstddef>
#include <cstdint>

// ---------------------------------------------------------------------------
// AttentionGoalState — round 7: 64x128 tiles (2x grid), all-bf16 chain,
// conv3 split-K via f32 atomics, bf16 HP2.
//
// Simplifications (exact up to fp rounding):
//   attn = softmax(KQ); Vn = V * attn.sum(axis=2) == V  (rowsums == 1)
//   -> K/Q GEMMs + S^2 softmax skipped entirely.
//
// GEMM: 64x128 tile, 4 waves (each 32x64 = 2x4 frags of 16x16x32 bf16),
// BK=32, global_load_lds(16B), double-buffered LDS, counted vmcnt(3).
// A and B in LDS as [kg][slot][8]: fragment ds_read_b128 is 256B-contiguous
// across 16 lanes = conflict-free (verified R5: conflicts == 0).
// ---------------------------------------------------------------------------

static constexpr int B_ = 8, TC = 6, TF = 4, DIN = 1024, DFF = 512, DOUT = 128;
static constexpr int HWP = 144;
static constexpr int P_CTX = B_ * TC * HWP;      // 6912
static constexpr int NF = B_ * TF;               // 32
static constexpr int P_FRM = NF * HWP;           // 4608
static constexpr int P_H1 = NF * 24 * 24;        // 18432
static constexpr int P_H2 = NF * 48 * 48;        // 73728
static constexpr int S2 = 48 * 48;               // 2304
static constexpr int NPOS = 3200;                // 8*4*10*10 conv3d outputs

// workspace offsets in float slots (phase-aliased; peak ~53 MB)
// phase A (nonlocal):
static constexpr size_t OFF_XB   = 0;          // P_CTX*DIN bf16 = 3,538,944 slots
static constexpr size_t OFF_YB   = 3538944;    // P_CTX*DIN bf16
static constexpr size_t OFF_VNB  = 7077888;    // P_CTX*DFF bf16 = 1,769,472
static constexpr size_t OFF_WB1  = 8847360;    // 262,144
static constexpr size_t OFF_WB2  = 9109504;    // 262,144
static constexpr size_t OFF_ST   = 9371648;    // 4,096 f32
// phase B (conv3; XB live, YB/VNB dead):
static constexpr size_t OFF_TWB  = 3538944;    // 27*1024*128 bf16 = 1,769,472 slots
static constexpr size_t OFF_R    = 5308416;    // 409,600 f32
// phase C (upsample/attn; all above dead):
static constexpr size_t OFF_F0B  = 0;          // P_FRM*DIN bf16 = 2,359,296 slots
static constexpr size_t OFF_W1B  = 2359296;    // 1,048,576
static constexpr size_t OFF_W2B  = 3407872;    // 131,072
static constexpr size_t OFF_HP1B = 3538944;    // P_H1*DFF bf16 = 4,718,592
static constexpr size_t OFF_HP2B = 8257536;    // P_H2*DOUT bf16 = 4,718,592
static constexpr size_t OFF_SG   = 12976128;   // 73,728 f32
static constexpr size_t OFF_PP   = 13049856;   // 147,456 f32

typedef __attribute__((ext_vector_type(8))) short bf16x8;
typedef __attribute__((ext_vector_type(4))) float f32x4;
typedef __attribute__((ext_vector_type(4))) unsigned short us4;
typedef __attribute__((ext_vector_type(8))) unsigned short us8;

__device__ __forceinline__ unsigned short f2b(float f) {
    union { float f; uint32_t u; } x{f};
    uint32_t r = x.u + 0x7FFFu + ((x.u >> 16) & 1u);  // RNE
    return (unsigned short)(r >> 16);
}
__device__ __forceinline__ float b2f(unsigned short u) {
    union { uint32_t u; float f; } x;
    x.u = (uint32_t)u << 16;
    return x.f;
}

#define GL16(g, s)                                                        \
    __builtin_amdgcn_global_load_lds(                                     \
        (const __attribute__((address_space(1))) void*)(g),               \
        (__attribute__((address_space(3))) void*)(s), 16, 0, 0)

// --------------------------- helpers ---------------------------------------

__global__ __launch_bounds__(256) void zero_f32(float* p, int n) {
    int i = blockIdx.x * 256 + threadIdx.x;
    if (i < n) p[i] = 0.f;
}

// [F][C][HW] -> [F*HW][C] bf16 (tiled transpose, both sides coalesced)
__global__ __launch_bounds__(256) void transpose_cm_pm(const float* __restrict__ in,
                                                       unsigned short* __restrict__ outB,
                                                       int C, int HW) {
    __shared__ float T[64][17];
    int tx = threadIdx.x, ty = threadIdx.y;
    int f = blockIdx.z, hw0 = blockIdx.x * 16, c0 = blockIdx.y * 64;
#pragma unroll
    for (int i = 0; i < 4; ++i)
        T[ty + 16 * i][tx] = in[((size_t)f * C + c0 + ty + 16 * i) * HW + hw0 + tx];
    __syncthreads();
#pragma unroll
    for (int i = 0; i < 4; ++i)
        outB[((size_t)f * HW + hw0 + ty) * C + c0 + tx + 16 * i] = f2b(T[tx + 16 * i][ty]);
}

// weight [O][C] -> Bp[((c>>3)*O + o)*8 + (c&7)]
__global__ __launch_bounds__(256) void wb_plain(const float* __restrict__ in,
                                                unsigned short* __restrict__ out,
                                                int O, int C) {
    int t = blockIdx.x * 256 + threadIdx.x;
    if (t >= O * C) return;
    int kr = t & 7, o = (t >> 3) % O, kg = (t >> 3) / O;
    out[t] = f2b(in[(size_t)o * C + kg * 8 + kr]);
}

// tp_w [128][1024][27] -> TWB[tap][((c>>3)*128 + o)*8 + (c&7)]
__global__ __launch_bounds__(256) void wb_conv(const float* __restrict__ tp,
                                               unsigned short* __restrict__ out) {
    int t = blockIdx.x * 256 + threadIdx.x;
    if (t >= 27 * 1024 * 128) return;
    int kr = t & 7, o = (t >> 3) & 127, kg = (t >> 10) & 127, tap = t >> 17;
    int c = kg * 8 + kr;
    out[t] = f2b(tp[((size_t)o * 1024 + c) * 27 + tap]);
}

// up_w [C][O][2][2] -> WB[d][((c>>3)*O + o)*8 + (c&7)]
__global__ __launch_bounds__(256) void wb_convT(const float* __restrict__ uw,
                                                unsigned short* __restrict__ out,
                                                int O, int C) {
    int t = blockIdx.x * 256 + threadIdx.x;
    if (t >= 4 * O * C) return;
    int kr = t & 7, o = (t >> 3) % O;
    int rest = (t >> 3) / O;
    int kg = rest % (C / 8), d = rest / (C / 8);
    int c = kg * 8 + kr;
    out[t] = f2b(uw[((size_t)c * O + o) * 4 + d]);
}

// --------------------------- MFMA GEMM (64x128 tile) -------------------------
// C[M,N] = epi(A[M,K] x B[K,N]).  A bf16 row-major (GATHER: im2col rows),
// B interleaved [K/8][N][8].
// EPI bits: 1=bias 2=relu 4=resid(bf16) 8=bf16out 16=atomicF32.
// blockIdx.z: tap (conv3d GATHER) or quadrant d (convT REMAP).
template <int EPI, int REMAP, int GATHER>
__global__ __launch_bounds__(256) void gemm_mfma(
    const unsigned short* __restrict__ A, const unsigned short* __restrict__ Bp,
    const float* __restrict__ bias, const unsigned short* __restrict__ resid,
    void* __restrict__ Cv, int M, int N, int K, size_t bStrideZ,
    int inW, int inHW, int outW, int outSPP) {
    __shared__ unsigned short Al[2][64 * 32];   // [kg][row][8]
    __shared__ unsigned short Bl[2][128 * 32];  // [kg][n][8]
    __shared__ int sPix[64];
    int tid = threadIdx.x;
    int w = tid >> 6, l = tid & 63;
    int m0 = blockIdx.y * 64, n0 = blockIdx.x * 128;
    int z = blockIdx.z;
    const unsigned short* Bpz = Bp + (size_t)z * bStrideZ;

    if (GATHER) {
        if (tid < 64) {
            int pos = m0 + tid;
            int ww = pos % 10;
            int r = pos / 10;
            int h = r % 10;
            r /= 10;
            int t = r & 3, b = r >> 2;
            int dt = z / 9, rr = z - dt * 9;
            int doff = dt * 144 + (rr / 3) * 12 + (rr % 3);
            sPix[tid] = ((b * 6 + t) * 12 + h) * 12 + ww + doff;
        }
        __syncthreads();
    }

    int wr = w >> 1, wc = w & 1;
    int l15 = l & 15, lg = l >> 4;

    // bias preload BEFORE staging so the vmcnt FIFO analysis in the loop holds
    float bv[4];
#pragma unroll
    for (int ni = 0; ni < 4; ++ni)
        bv[ni] = (EPI & 1) ? bias[n0 + wc * 64 + ni * 16 + l15] : 0.f;
    asm volatile("s_waitcnt vmcnt(0)" ::: "memory");

    // A staging: wave w = k-chunk w; lane l stages row l.  1 GL16/thread.
    int grow = GATHER ? sPix[l] : (m0 + l);
    const unsigned short* ag = A + (size_t)grow * K + w * 8;
    const int aoff = (w * 64 + l) * 8;
    // B staging: 2 GL16/thread; chunk c covers kg = (tid>>7) + 2c, n = tid&127
    int bkg = tid >> 7, bn = tid & 127;
    const unsigned short* bg0 = Bpz + ((size_t)bkg * N + n0 + bn) * 8;
    const unsigned short* bg1 = Bpz + ((size_t)(bkg + 2) * N + n0 + bn) * 8;
    const int boff0 = tid * 8, boff1 = (tid + 256) * 8;
    size_t bstep = (size_t)32 * N;  // 4 kg * N * 8 elems per K-step

    f32x4 acc[2][4];
#pragma unroll
    for (int mi = 0; mi < 2; ++mi)
#pragma unroll
        for (int ni = 0; ni < 4; ++ni) acc[mi][ni] = (f32x4){0.f, 0.f, 0.f, 0.f};

    int nt = K >> 5;
    GL16(ag, &Al[0][aoff]);
    GL16(bg0, &Bl[0][boff0]);
    GL16(bg1, &Bl[0][boff1]);
    ag += 32;
    bg0 += bstep;
    bg1 += bstep;

    for (int t = 0; t < nt; ++t) {
        int cur = t & 1;
        if (t + 1 < nt) {
            int nx = cur ^ 1;
            GL16(ag, &Al[nx][aoff]);
            GL16(bg0, &Bl[nx][boff0]);
            GL16(bg1, &Bl[nx][boff1]);
            ag += 32;
            bg0 += bstep;
            bg1 += bstep;
            asm volatile("s_waitcnt vmcnt(3)" ::: "memory");
        } else {
            asm volatile("s_waitcnt vmcnt(0)" ::: "memory");
        }
        __builtin_amdgcn_s_barrier();
        __builtin_amdgcn_sched_barrier(0);
        bf16x8 af[2], bf[4];
#pragma unroll
        for (int mi = 0; mi < 2; ++mi)
            af[mi] = *(const bf16x8*)&Al[cur][(lg * 64 + wr * 32 + mi * 16 + l15) * 8];
#pragma unroll
        for (int ni = 0; ni < 4; ++ni)
            bf[ni] = *(const bf16x8*)&Bl[cur][(lg * 128 + wc * 64 + ni * 16 + l15) * 8];
#pragma unroll
        for (int mi = 0; mi < 2; ++mi)
#pragma unroll
            for (int ni = 0; ni < 4; ++ni)
                acc[mi][ni] = __builtin_amdgcn_mfma_f32_16x16x32_bf16(
                    af[mi], bf[ni], acc[mi][ni], 0, 0, 0);
        __builtin_amdgcn_sched_barrier(0);
        __builtin_amdgcn_s_barrier();
    }

    // epilogue
    float* Cf = (float*)Cv;
    unsigned short* Cb = (unsigned short*)Cv;
#pragma unroll
    for (int mi = 0; mi < 2; ++mi) {
#pragma unroll
        for (int r = 0; r < 4; ++r) {
            int m = m0 + wr * 32 + mi * 16 + lg * 4 + r;
            int orow = m;
            if (REMAP) {
                int ni_ = m / inHW;
                int rem = m - ni_ * inHW;
                int h = rem / inW, ww = rem - h * inW;
                orow = ni_ * outSPP + (2 * h + (z >> 1)) * outW + (2 * ww + (z & 1));
            }
#pragma unroll
            for (int ni = 0; ni < 4; ++ni) {
                int n = n0 + wc * 64 + ni * 16 + l15;
                float v = acc[mi][ni][r];
                if (EPI & 16) {
                    atomicAdd(&Cf[(size_t)orow * N + n], v);
                } else {
                    v += bv[ni];
                    if (EPI & 2) v = fmaxf(v, 0.f);
                    if (EPI & 4) v += b2f(resid[(size_t)m * N + n]);
                    if (EPI & 8)
                        Cb[(size_t)orow * N + n] = f2b(v);
                    else
                        Cf[(size_t)orow * N + n] = v;
                }
            }
        }
    }
}

// --------------------------- conv3d tail -------------------------------------
// R holds raw conv sums (atomics); bias+relu+mean fused here.
__global__ __launch_bounds__(128) void goal_reduce(const float* __restrict__ R,
                                                   const float* __restrict__ bias,
                                                   float* __restrict__ out) {
    int b = blockIdx.x, o = threadIdx.x;
    float bo = bias[o];
    float s = 0.f;
    for (int i = 0; i < 400; ++i)
        s += fmaxf(R[(size_t)(b * 400 + i) * 128 + o] + bo, 0.f);
    out[b * 128 + o] = s * (1.f / 400.f);
}

// --------------------------- BatchNorm (bf16 in) -----------------------------

__global__ __launch_bounds__(256) void bn_stats_b(const unsigned short* __restrict__ YB,
                                                  float* __restrict__ st) {
    int tid = threadIdx.x;
    int p0 = blockIdx.x * 64;
    int c0 = tid * 4;
    float s[4] = {0, 0, 0, 0}, q[4] = {0, 0, 0, 0};
    for (int pp = 0; pp < 64; ++pp) {
        us4 y = *(const us4*)(YB + (size_t)(p0 + pp) * 1024 + c0);
#pragma unroll
        for (int j = 0; j < 4; ++j) {
            float v = b2f(y[j]);
            s[j] += v;
            q[j] += v * v;
        }
    }
#pragma unroll
    for (int j = 0; j < 4; ++j) {
        atomicAdd(&st[c0 + j], s[j]);
        atomicAdd(&st[1024 + c0 + j], q[j]);
    }
}

__global__ __launch_bounds__(256) void bn_final(float* __restrict__ st,
                                                const float* __restrict__ gamma,
                                                const float* __restrict__ beta) {
    int c = blockIdx.x * 256 + threadIdx.x;
    if (c >= 1024) return;
    const float invn = 1.f / 6912.f;
    float mean = st[c] * invn;
    float var = st[1024 + c] * invn - mean * mean;
    float sc = gamma[c] * rsqrtf(var + 1e-5f);
    st[2048 + c] = sc;
    st[3072 + c] = beta[c] - mean * sc;
}

// XB = scale*YB + shift  (bf16 -> bf16)
__global__ __launch_bounds__(256) void bn_apply_b(const unsigned short* __restrict__ YB,
                                                  unsigned short* __restrict__ XB,
                                                  const float* __restrict__ st) {
    const float* scale = st + 2048;
    const float* shift = st + 3072;
    int idx = blockIdx.x * 256 + threadIdx.x;  // over P_CTX*1024/4
    int c0 = (idx & 255) << 2;
    us4 y = ((const us4*)YB)[idx];
    us4 o;
#pragma unroll
    for (int j = 0; j < 4; ++j) o[j] = f2b(b2f(y[j]) * scale[c0 + j] + shift[c0 + j]);
    ((us4*)XB)[idx] = o;
}

// --------------------------- final goal/state attention ----------------------

__global__ __launch_bounds__(256) void attn_logits(const unsigned short* __restrict__ Hp2,
                                                   const float* __restrict__ out,
                                                   float* __restrict__ SG) {
    int n = blockIdx.y;
    int tid = threadIdx.x;
    int s = blockIdx.x * 16 + (tid >> 4);
    int l16 = tid & 15;
    us8 row = *((const us8*)(Hp2 + ((size_t)n * S2 + s) * 128) + l16);
    const float* g = out + (n & 7) * 128 + l16 * 8;
    float dot = 0.f;
#pragma unroll
    for (int i = 0; i < 8; ++i) dot += b2f(row[i]) * g[i];
    dot += __shfl_xor(dot, 1);
    dot += __shfl_xor(dot, 2);
    dot += __shfl_xor(dot, 4);
    dot += __shfl_xor(dot, 8);
    if (l16 == 0) SG[(size_t)n * S2 + s] = dot * 0.0883883476483184f;
}

__global__ __launch_bounds__(256) void attn_softmax(float* __restrict__ SG) {
    __shared__ float red[256];
    int n = blockIdx.x, tid = threadIdx.x;
    float* row = SG + (size_t)n * S2;
    float v[9];
    float lmax = -3.4e38f;
#pragma unroll
    for (int i = 0; i < 9; ++i) {
        v[i] = row[tid + 256 * i];
        lmax = fmaxf(lmax, v[i]);
    }
    red[tid] = lmax;
    __syncthreads();
    for (int off = 128; off > 0; off >>= 1) {
        if (tid < off) red[tid] = fmaxf(red[tid], red[tid + off]);
        __syncthreads();
    }
    float m = red[0];
    __syncthreads();
    float ls = 0.f;
#pragma unroll
    for (int i = 0; i < 9; ++i) {
        v[i] = expf(v[i] - m);
        ls += v[i];
    }
    red[tid] = ls;
    __syncthreads();
    for (int off = 128; off > 0; off >>= 1) {
        if (tid < off) red[tid] += red[tid + off];
        __syncthreads();
    }
    float inv = 1.f / red[0];
#pragma unroll
    for (int i = 0; i < 9; ++i) row[tid + 256 * i] = v[i] * inv;
}

__global__ __launch_bounds__(256) void attn_pv(const unsigned short* __restrict__ Hp2,
                                               const float* __restrict__ SG,
                                               float* __restrict__ PP) {
    int n = blockIdx.y;
    int sb = blockIdx.x;
    int tid = threadIdx.x;
    int d = tid & 127, half = tid >> 7;
    int s0 = sb * 128 + half * 64;
    float freq = expf(-(float)(d & ~1) * (9.210340371976184f / 128.f));
    bool odd = d & 1;
    const float* att = SG + (size_t)n * S2;
    float acc = 0.f;
    for (int i = 0; i < 64; ++i) {
        int s = s0 + i;
        float ang = (float)s * freq;
        float pe = odd ? cosf(ang) : sinf(ang);
        acc += att[s] * (b2f(Hp2[((size_t)n * S2 + s) * 128 + d]) + pe);
    }
    PP[((size_t)n * 18 + sb) * 256 + tid] = acc;
}

__global__ __launch_bounds__(128) void attn_pv_reduce(const float* __restrict__ PP,
                                                      float* __restrict__ out) {
    int n = blockIdx.x, d = threadIdx.x;
    float s = 0.f;
    for (int i = 0; i < 18; ++i) {
        const float* p = PP + ((size_t)n * 18 + i) * 256;
        s += p[d] + p[128 + d];
    }
    out[1024 + n * 128 + d] = s;
}

// --------------------------- launch ------------------------------------------

extern "C" void kernel_launch(void* const* d_in, const int* in_sizes, int n_in,
                              void* d_out, int out_size, void* d_ws, size_t ws_size,
                              hipStream_t stream) {
    const float* context = (const float*)d_in[0];
    const float* frame = (const float*)d_in[1];
    const float* Vw = (const float*)d_in[6];
    const float* Vb = (const float*)d_in[7];
    const float* Ow = (const float*)d_in[8];
    const float* Ob = (const float*)d_in[9];
    const float* gamma = (const float*)d_in[10];
    const float* beta = (const float*)d_in[11];
    const float* tpw = (const float*)d_in[12];
    const float* tpb = (const float*)d_in[13];
    const float* u1w = (const float*)d_in[14];
    const float* u1b = (const float*)d_in[15];
    const float* u2w = (const float*)d_in[16];
    const float* u2b = (const float*)d_in[17];
    float* ws = (float*)d_ws;
    float* out = (float*)d_out;

    unsigned short* XB = (unsigned short*)(ws + OFF_XB);
    unsigned short* YB = (unsigned short*)(ws + OFF_YB);
    unsigned short* VNB = (unsigned short*)(ws + OFF_VNB);
    unsigned short* WB1 = (unsigned short*)(ws + OFF_WB1);
    unsigned short* WB2 = (unsigned short*)(ws + OFF_WB2);
    float* ST = ws + OFF_ST;
    unsigned short* TWB = (unsigned short*)(ws + OFF_TWB);
    float* R = ws + OFF_R;
    unsigned short* F0B = (unsigned short*)(ws + OFF_F0B);
    unsigned short* W1B = (unsigned short*)(ws + OFF_W1B);
    unsigned short* W2B = (unsigned short*)(ws + OFF_W2B);
    unsigned short* HP1B = (unsigned short*)(ws + OFF_HP1B);
    unsigned short* HP2B = (unsigned short*)(ws + OFF_HP2B);
    float* SG = ws + OFF_SG;
    float* PP = ws + OFF_PP;

    // context [8][6][1024][144] -> XB bf16 (pixel-major)
    transpose_cm_pm<<<dim3(HWP / 16, DIN / 64, B_ * TC), dim3(16, 16), 0, stream>>>(
        context, XB, DIN, HWP);

    for (int l = 0; l < 2; ++l) {
        wb_plain<<<(DFF * DIN) / 256, 256, 0, stream>>>(Vw + (size_t)l * DFF * DIN, WB1, DFF, DIN);
        wb_plain<<<(DIN * DFF) / 256, 256, 0, stream>>>(Ow + (size_t)l * DIN * DFF, WB2, DIN, DFF);
        // VN = relu(X*Vw^T + Vb)  [bf16]
        gemm_mfma<11, 0, 0><<<dim3(DFF / 128, P_CTX / 64, 1), 256, 0, stream>>>(
            XB, WB1, Vb + l * DFF, nullptr, VNB, P_CTX, DFF, DIN, 0, 0, 0, 0, 0);
        // Y = X + relu(VN*Ow^T + Ob)  [bf16; resid = XB bf16]
        gemm_mfma<15, 0, 0><<<dim3(DIN / 128, P_CTX / 64, 1), 256, 0, stream>>>(
            VNB, WB2, Ob + l * DIN, XB, YB, P_CTX, DIN, DFF, 0, 0, 0, 0, 0);
        // BatchNorm (training-mode stats); XB <- BN(YB)
        zero_f32<<<8, 256, 0, stream>>>(ST, 2048);
        bn_stats_b<<<P_CTX / 64, 256, 0, stream>>>(YB, ST);
        bn_final<<<4, 256, 0, stream>>>(ST, gamma + l * DIN, beta + l * DIN);
        bn_apply_b<<<(P_CTX * DIN / 4) / 256, 256, 0, stream>>>(YB, XB, ST);
    }

    // temporal pool: split-K over 27 taps, f32 atomics into R
    wb_conv<<<(27 * DIN * DOUT) / 256, 256, 0, stream>>>(tpw, TWB);
    zero_f32<<<(NPOS * DOUT) / 256, 256, 0, stream>>>(R, NPOS * DOUT);
    gemm_mfma<16, 0, 1><<<dim3(1, NPOS / 64, 27), 256, 0, stream>>>(
        XB, TWB, nullptr, nullptr, R, NPOS, DOUT, DIN,
        (size_t)DIN / 8 * DOUT * 8, 0, 0, 0, 0);
    goal_reduce<<<8, 128, 0, stream>>>(R, tpb, out);

    // frame upsample path (bf16 throughout)
    transpose_cm_pm<<<dim3(HWP / 16, DIN / 64, NF), dim3(16, 16), 0, stream>>>(
        frame, F0B, DIN, HWP);
    wb_convT<<<(4 * DIN * DFF) / 256, 256, 0, stream>>>(u1w, W1B, DFF, DIN);
    wb_convT<<<(4 * DFF * DOUT) / 256, 256, 0, stream>>>(u2w, W2B, DOUT, DFF);
    // up1: relu(convT1), 4 quadrants via z, bf16 out with row remap
    gemm_mfma<11, 1, 0><<<dim3(DFF / 128, P_FRM / 64, 4), 256, 0, stream>>>(
        F0B, W1B, u1b, nullptr, HP1B, P_FRM, DFF, DIN,
        (size_t)DIN / 8 * DFF * 8, 12, 144, 24, 576);
    // up2: convT2 (no relu), bf16 out with row remap -> HP2B
    gemm_mfma<9, 1, 0><<<dim3(DOUT / 128, P_H1 / 64, 4), 256, 0, stream>>>(
        HP1B, W2B, u2b, nullptr, HP2B, P_H1, DOUT, DFF,
        (size_t)DFF / 8 * DOUT * 8, 24, 576, 48, 2304);

    // final goal/state attention
    attn_logits<<<dim3(S2 / 16, NF), 256, 0, stream>>>(HP2B, out, SG);
    attn_softmax<<<NF, 256, 0, stream>>>(SG);
    attn_pv<<<dim3(18, NF), 256, 0, stream>>>(HP2B, SG, PP);
    attn_pv_reduce<<<NF, 128, 0, stream>>>(PP, out);
}

// Round 8
// 361.627 us; speedup vs baseline: 1.0462x; 1.0462x over previous
//
#include <hip/hip_runtime.h>
#include <cstddef>
#include <cstdint>

// ---------------------------------------------------------------------------
// AttentionGoalState — round 8: conv3 back to split-K partials (atomics were
// 27-way contended), depth-2 prefetch (3 LDS buffers, counted vmcnt), single
// weight-prep kernel.  All-bf16 activation chain kept from R7.
//
// Simplifications (exact up to fp rounding):
//   attn = softmax(KQ); Vn = V * attn.sum(axis=2) == V  (rowsums == 1)
//   -> K/Q GEMMs + S^2 softmax skipped entirely.
//
// GEMM: 64x128 tile, 4 waves (each 32x64 = 2x4 frags of 16x16x32 bf16),
// BK=32, global_load_lds(16B), TRIPLE-buffered LDS (prefetch depth 2):
//   iter t: stage buf[(t+2)%3] -> vmcnt(6) -> s_barrier -> MFMA buf[t%3]
//   -> s_barrier.  FIFO vmcnt: 6 = 2 tiles in flight x 3 loads/thread.
// A and B in LDS as [kg][slot][8]: fragment ds_read_b128 is 256B-contiguous
// across 16 lanes = conflict-free (verified R5: conflicts == 0).
// ---------------------------------------------------------------------------

static constexpr int B_ = 8, TC = 6, TF = 4, DIN = 1024, DFF = 512, DOUT = 128;
static constexpr int HWP = 144;
static constexpr int P_CTX = B_ * TC * HWP;      // 6912
static constexpr int NF = B_ * TF;               // 32
static constexpr int P_FRM = NF * HWP;           // 4608
static constexpr int P_H1 = NF * 24 * 24;        // 18432
static constexpr int P_H2 = NF * 48 * 48;        // 73728
static constexpr int S2 = 48 * 48;               // 2304
static constexpr int NPOS = 3200;                // 8*4*10*10 conv3d outputs

// ---- workspace offsets in FLOAT slots (peak ~97 MB) ----
// phase A (nonlocal), later aliased by upsample phase:
static constexpr size_t OFF_XB   = 0;          // 7,077,888 bf16 = 3,538,944 slots
static constexpr size_t OFF_YB   = 3538944;    // 7,077,888 bf16
static constexpr size_t OFF_VNB  = 7077888;    // 3,538,944 bf16 = 1,769,472 slots
static constexpr size_t OFF_WB1  = 8847360;    // 2 layers x 524,288 bf16 = 524,288 slots
static constexpr size_t OFF_WB2  = 9371648;    // 2 layers x 524,288 bf16
static constexpr size_t OFF_ST   = 9895936;    // 4,096 f32
// persistent weights (written by prep, live through conv3/upsample):
static constexpr size_t OFF_TWB  = 9900032;    // 3,538,944 bf16 = 1,769,472 slots
static constexpr size_t OFF_W1B  = 11669504;   // 2,097,152 bf16 = 1,048,576 slots
static constexpr size_t OFF_W2B  = 12718080;   // 262,144 bf16 = 131,072 slots
// conv3 phase:
static constexpr size_t OFF_GP   = 12849152;   // 27*3200*128 f32 = 11,059,200 slots
static constexpr size_t OFF_R    = 23908352;   // 409,600 f32
// upsample phase (aliases phase A region; W1B/W2B still live):
static constexpr size_t OFF_F0B  = 0;          // 4,718,592 bf16 = 2,359,296 slots
static constexpr size_t OFF_HP1B = 2359296;    // 9,437,184 bf16 = 4,718,592 slots
static constexpr size_t OFF_HP2B = 7077888;    // 9,437,184 bf16 (tail overlaps dead TWB/W1B only after up1)
// attn scratch (aliases dead GP):
static constexpr size_t OFF_SG   = 12849152;   // 73,728 f32
static constexpr size_t OFF_PP   = 12922880;   // 147,456 f32

typedef __attribute__((ext_vector_type(8))) short bf16x8;
typedef __attribute__((ext_vector_type(4))) float f32x4;
typedef __attribute__((ext_vector_type(4))) unsigned short us4;
typedef __attribute__((ext_vector_type(8))) unsigned short us8;

__device__ __forceinline__ unsigned short f2b(float f) {
    union { float f; uint32_t u; } x{f};
    uint32_t r = x.u + 0x7FFFu + ((x.u >> 16) & 1u);  // RNE
    return (unsigned short)(r >> 16);
}
__device__ __forceinline__ float b2f(unsigned short u) {
    union { uint32_t u; float f; } x;
    x.u = (uint32_t)u << 16;
    return x.f;
}

#define GL16(g, s)                                                        \
    __builtin_amdgcn_global_load_lds(                                     \
        (const __attribute__((address_space(1))) void*)(g),               \
        (__attribute__((address_space(3))) void*)(s), 16, 0, 0)

// --------------------------- helpers ---------------------------------------

__global__ __launch_bounds__(256) void zero_f32(float* p, int n) {
    int i = blockIdx.x * 256 + threadIdx.x;
    if (i < n) p[i] = 0.f;
}

// [F][C][HW] -> [F*HW][C] bf16 (tiled transpose, both sides coalesced)
__global__ __launch_bounds__(256) void transpose_cm_pm(const float* __restrict__ in,
                                                       unsigned short* __restrict__ outB,
                                                       int C, int HW) {
    __shared__ float T[64][17];
    int tx = threadIdx.x, ty = threadIdx.y;
    int f = blockIdx.z, hw0 = blockIdx.x * 16, c0 = blockIdx.y * 64;
#pragma unroll
    for (int i = 0; i < 4; ++i)
        T[ty + 16 * i][tx] = in[((size_t)f * C + c0 + ty + 16 * i) * HW + hw0 + tx];
    __syncthreads();
#pragma unroll
    for (int i = 0; i < 4; ++i)
        outB[((size_t)f * HW + hw0 + ty) * C + c0 + tx + 16 * i] = f2b(T[tx + 16 * i][ty]);
}

// ---- one-shot weight prep: all weights -> bf16 interleaved [K/8][N][8] ----
static constexpr int PW0 = 4 * 524288;             // Vw0,Ow0,Vw1,Ow1
static constexpr int PW1 = PW0 + 27 * 1024 * 128;  // + TWB
static constexpr int PW2 = PW1 + 4 * 512 * 1024;   // + W1B
static constexpr int PW3 = PW2 + 4 * 128 * 512;    // + W2B
__global__ __launch_bounds__(256) void prep_weights(
    const float* __restrict__ Vw, const float* __restrict__ Ow,
    const float* __restrict__ tp, const float* __restrict__ u1w,
    const float* __restrict__ u2w,
    unsigned short* __restrict__ WB1, unsigned short* __restrict__ WB2,
    unsigned short* __restrict__ TWB, unsigned short* __restrict__ W1B,
    unsigned short* __restrict__ W2B) {
    int t = blockIdx.x * 256 + threadIdx.x;
    if (t < PW0) {
        int which = t >> 19;        // 0:Vw0 1:Ow0 2:Vw1 3:Ow1
        int r = t & 524287;
        int kr = r & 7;
        int layer = which >> 1;
        if ((which & 1) == 0) {     // Vw: O=512, C=1024
            int o = (r >> 3) & 511, kg = (r >> 3) >> 9;
            WB1[(size_t)layer * 524288 + r] =
                f2b(Vw[(size_t)layer * 524288 + (size_t)o * 1024 + kg * 8 + kr]);
        } else {                    // Ow: O=1024, C=512
            int o = (r >> 3) & 1023, kg = (r >> 3) >> 10;
            WB2[(size_t)layer * 524288 + r] =
                f2b(Ow[(size_t)layer * 524288 + (size_t)o * 512 + kg * 8 + kr]);
        }
    } else if (t < PW1) {           // tp_w [128][1024][27] -> [tap][kg*128+o][8]
        int r = t - PW0;
        int kr = r & 7, o = (r >> 3) & 127, kg = (r >> 10) & 127, tap = r >> 17;
        int c = kg * 8 + kr;
        TWB[r] = f2b(tp[((size_t)o * 1024 + c) * 27 + tap]);
    } else if (t < PW2) {           // u1w [1024][512][2][2]: O=512, C=1024
        int r = t - PW1;
        int kr = r & 7, o = (r >> 3) % 512;
        int rest = (r >> 3) / 512;
        int kg = rest & 127, d = rest >> 7;
        W1B[r] = f2b(u1w[((size_t)(kg * 8 + kr) * 512 + o) * 4 + d]);
    } else if (t < PW3) {           // u2w [512][128][2][2]: O=128, C=512
        int r = t - PW2;
        int kr = r & 7, o = (r >> 3) & 127;
        int rest = (r >> 3) >> 7;
        int kg = rest & 63, d = rest >> 6;
        W2B[r] = f2b(u2w[((size_t)(kg * 8 + kr) * 128 + o) * 4 + d]);
    }
}

// --------------------------- MFMA GEMM (64x128 tile, 3-buf) ------------------
// C[M,N] = epi(A[M,K] x B[K,N]).  A bf16 row-major (GATHER: im2col rows),
// B interleaved [K/8][N][8].
// EPI bits: 1=bias 2=relu 4=resid(bf16) 8=bf16out  (else f32 out + cStrideZ).
// blockIdx.z: tap (conv3d GATHER) or quadrant d (convT REMAP).
template <int EPI, int REMAP, int GATHER>
__global__ __launch_bounds__(256) void gemm_mfma(
    const unsigned short* __restrict__ A, const unsigned short* __restrict__ Bp,
    const float* __restrict__ bias, const unsigned short* __restrict__ resid,
    void* __restrict__ Cv, int M, int N, int K,
    size_t bStrideZ, size_t cStrideZ,
    int inW, int inHW, int outW, int outSPP) {
    __shared__ unsigned short Al[3][64 * 32];   // [kg][row][8]
    __shared__ unsigned short Bl[3][128 * 32];  // [kg][n][8]
    __shared__ int sPix[64];
    int tid = threadIdx.x;
    int w = tid >> 6, l = tid & 63;
    int m0 = blockIdx.y * 64, n0 = blockIdx.x * 128;
    int z = blockIdx.z;
    const unsigned short* Bpz = Bp + (size_t)z * bStrideZ;

    if (GATHER) {
        if (tid < 64) {
            int pos = m0 + tid;
            int ww = pos % 10;
            int r = pos / 10;
            int h = r % 10;
            r /= 10;
            int t = r & 3, b = r >> 2;
            int dt = z / 9, rr = z - dt * 9;
            int doff = dt * 144 + (rr / 3) * 12 + (rr % 3);
            sPix[tid] = ((b * 6 + t) * 12 + h) * 12 + ww + doff;
        }
        __syncthreads();
    }

    int wr = w >> 1, wc = w & 1;
    int l15 = l & 15, lg = l >> 4;

    // bias preload BEFORE staging so the vmcnt FIFO analysis in the loop holds
    float bv[4];
#pragma unroll
    for (int ni = 0; ni < 4; ++ni)
        bv[ni] = (EPI & 1) ? bias[n0 + wc * 64 + ni * 16 + l15] : 0.f;
    asm volatile("s_waitcnt vmcnt(0)" ::: "memory");

    // A staging: wave w = k-chunk w; lane l stages row l.  1 GL16/thread.
    int grow = GATHER ? sPix[l] : (m0 + l);
    const unsigned short* ag = A + (size_t)grow * K + w * 8;
    const int aoff = (w * 64 + l) * 8;
    // B staging: 2 GL16/thread; kg = (tid>>7) + 2c, n = tid&127
    int bkg = tid >> 7, bn = tid & 127;
    const unsigned short* bg0 = Bpz + ((size_t)bkg * N + n0 + bn) * 8;
    const unsigned short* bg1 = Bpz + ((size_t)(bkg + 2) * N + n0 + bn) * 8;
    const int boff0 = tid * 8, boff1 = (tid + 256) * 8;
    size_t bstep = (size_t)32 * N;  // 4 kg * N * 8 elems per K-step

    f32x4 acc[2][4];
#pragma unroll
    for (int mi = 0; mi < 2; ++mi)
#pragma unroll
        for (int ni = 0; ni < 4; ++ni) acc[mi][ni] = (f32x4){0.f, 0.f, 0.f, 0.f};

    int nt = K >> 5;  // >= 16 for all our shapes
    // prologue: stage buffers 0 and 1
    GL16(ag, &Al[0][aoff]);
    GL16(bg0, &Bl[0][boff0]);
    GL16(bg1, &Bl[0][boff1]);
    ag += 32; bg0 += bstep; bg1 += bstep;
    GL16(ag, &Al[1][aoff]);
    GL16(bg0, &Bl[1][boff0]);
    GL16(bg1, &Bl[1][boff1]);
    ag += 32; bg0 += bstep; bg1 += bstep;

    int bc = 0, sb = 2;
    for (int t = 0; t < nt; ++t) {
        if (t + 2 < nt) {
            GL16(ag, &Al[sb][aoff]);
            GL16(bg0, &Bl[sb][boff0]);
            GL16(bg1, &Bl[sb][boff1]);
            ag += 32; bg0 += bstep; bg1 += bstep;
            // t's 3 loads retired; t+1 and t+2 (6 loads) stay in flight
            asm volatile("s_waitcnt vmcnt(6)" ::: "memory");
        } else if (t + 1 < nt) {
            asm volatile("s_waitcnt vmcnt(3)" ::: "memory");
        } else {
            asm volatile("s_waitcnt vmcnt(0)" ::: "memory");
        }
        __builtin_amdgcn_s_barrier();
        __builtin_amdgcn_sched_barrier(0);
        bf16x8 af[2], bf[4];
#pragma unroll
        for (int mi = 0; mi < 2; ++mi)
            af[mi] = *(const bf16x8*)&Al[bc][(lg * 64 + wr * 32 + mi * 16 + l15) * 8];
#pragma unroll
        for (int ni = 0; ni < 4; ++ni)
            bf[ni] = *(const bf16x8*)&Bl[bc][(lg * 128 + wc * 64 + ni * 16 + l15) * 8];
#pragma unroll
        for (int mi = 0; mi < 2; ++mi)
#pragma unroll
            for (int ni = 0; ni < 4; ++ni)
                acc[mi][ni] = __builtin_amdgcn_mfma_f32_16x16x32_bf16(
                    af[mi], bf[ni], acc[mi][ni], 0, 0, 0);
        __builtin_amdgcn_sched_barrier(0);
        __builtin_amdgcn_s_barrier();
        bc = (bc == 2) ? 0 : bc + 1;
        sb = (sb == 2) ? 0 : sb + 1;
    }

    // epilogue
    float* Cf = (float*)Cv + (size_t)z * cStrideZ;
    unsigned short* Cb = (unsigned short*)Cv;
#pragma unroll
    for (int mi = 0; mi < 2; ++mi) {
#pragma unroll
        for (int r = 0; r < 4; ++r) {
            int m = m0 + wr * 32 + mi * 16 + lg * 4 + r;
            int orow = m;
            if (REMAP) {
                int ni_ = m / inHW;
                int rem = m - ni_ * inHW;
                int h = rem / inW, ww = rem - h * inW;
                orow = ni_ * outSPP + (2 * h + (z >> 1)) * outW + (2 * ww + (z & 1));
            }
#pragma unroll
            for (int ni = 0; ni < 4; ++ni) {
                int n = n0 + wc * 64 + ni * 16 + l15;
                float v = acc[mi][ni][r] + bv[ni];
                if (EPI & 2) v = fmaxf(v, 0.f);
                if (EPI & 4) v += b2f(resid[(size_t)m * N + n]);
                if (EPI & 8)
                    Cb[(size_t)orow * N + n] = f2b(v);
                else
                    Cf[(size_t)orow * N + n] = v;
            }
        }
    }
}

// --------------------------- conv3d tail -------------------------------------

// sum 27 tap-partials, + bias, relu -> R[3200][128]
__global__ __launch_bounds__(256) void conv3_reduce(const float* __restrict__ Gp,
                                                    const float* __restrict__ bias,
                                                    float* __restrict__ R) {
    int idx = blockIdx.x * 256 + threadIdx.x;  // 3200*128
    float s = 0.f;
    for (int tap = 0; tap < 27; ++tap) s += Gp[(size_t)tap * (NPOS * 128) + idx];
    R[idx] = fmaxf(s + bias[idx & 127], 0.f);
}

__global__ __launch_bounds__(128) void goal_reduce(const float* __restrict__ R,
                                                   float* __restrict__ out) {
    int b = blockIdx.x, o = threadIdx.x;
    float s = 0.f;
    for (int i = 0; i < 400; ++i) s += R[(size_t)(b * 400 + i) * 128 + o];
    out[b * 128 + o] = s * (1.f / 400.f);
}

// --------------------------- BatchNorm (bf16 in) -----------------------------

__global__ __launch_bounds__(256) void bn_stats_b(const unsigned short* __restrict__ YB,
                                                  float* __restrict__ st) {
    int tid = threadIdx.x;
    int p0 = blockIdx.x * 64;
    int c0 = tid * 4;
    float s[4] = {0, 0, 0, 0}, q[4] = {0, 0, 0, 0};
    for (int pp = 0; pp < 64; ++pp) {
        us4 y = *(const us4*)(YB + (size_t)(p0 + pp) * 1024 + c0);
#pragma unroll
        for (int j = 0; j < 4; ++j) {
            float v = b2f(y[j]);
            s[j] += v;
            q[j] += v * v;
        }
    }
#pragma unroll
    for (int j = 0; j < 4; ++j) {
        atomicAdd(&st[c0 + j], s[j]);
        atomicAdd(&st[1024 + c0 + j], q[j]);
    }
}

__global__ __launch_bounds__(256) void bn_final(float* __restrict__ st,
                                                const float* __restrict__ gamma,
                                                const float* __restrict__ beta) {
    int c = blockIdx.x * 256 + threadIdx.x;
    if (c >= 1024) return;
    const float invn = 1.f / 6912.f;
    float mean = st[c] * invn;
    float var = st[1024 + c] * invn - mean * mean;
    float sc = gamma[c] * rsqrtf(var + 1e-5f);
    st[2048 + c] = sc;
    st[3072 + c] = beta[c] - mean * sc;
}

// XB = scale*YB + shift  (bf16 -> bf16)
__global__ __launch_bounds__(256) void bn_apply_b(const unsigned short* __restrict__ YB,
                                                  unsigned short* __restrict__ XB,
                                                  const float* __restrict__ st) {
    const float* scale = st + 2048;
    const float* shift = st + 3072;
    int idx = blockIdx.x * 256 + threadIdx.x;  // over P_CTX*1024/4
    int c0 = (idx & 255) << 2;
    us4 y = ((const us4*)YB)[idx];
    us4 o;
#pragma unroll
    for (int j = 0; j < 4; ++j) o[j] = f2b(b2f(y[j]) * scale[c0 + j] + shift[c0 + j]);
    ((us4*)XB)[idx] = o;
}

// --------------------------- final goal/state attention ----------------------

__global__ __launch_bounds__(256) void attn_logits(const unsigned short* __restrict__ Hp2,
                                                   const float* __restrict__ out,
                                                   float* __restrict__ SG) {
    int n = blockIdx.y;
    int tid = threadIdx.x;
    int s = blockIdx.x * 16 + (tid >> 4);
    int l16 = tid & 15;
    us8 row = *((const us8*)(Hp2 + ((size_t)n * S2 + s) * 128) + l16);
    const float* g = out + (n & 7) * 128 + l16 * 8;
    float dot = 0.f;
#pragma unroll
    for (int i = 0; i < 8; ++i) dot += b2f(row[i]) * g[i];
    dot += __shfl_xor(dot, 1);
    dot += __shfl_xor(dot, 2);
    dot += __shfl_xor(dot, 4);
    dot += __shfl_xor(dot, 8);
    if (l16 == 0) SG[(size_t)n * S2 + s] = dot * 0.0883883476483184f;
}

__global__ __launch_bounds__(256) void attn_softmax(float* __restrict__ SG) {
    __shared__ float red[256];
    int n = blockIdx.x, tid = threadIdx.x;
    float* row = SG + (size_t)n * S2;
    float v[9];
    float lmax = -3.4e38f;
#pragma unroll
    for (int i = 0; i < 9; ++i) {
        v[i] = row[tid + 256 * i];
        lmax = fmaxf(lmax, v[i]);
    }
    red[tid] = lmax;
    __syncthreads();
    for (int off = 128; off > 0; off >>= 1) {
        if (tid < off) red[tid] = fmaxf(red[tid], red[tid + off]);
        __syncthreads();
    }
    float m = red[0];
    __syncthreads();
    float ls = 0.f;
#pragma unroll
    for (int i = 0; i < 9; ++i) {
        v[i] = expf(v[i] - m);
        ls += v[i];
    }
    red[tid] = ls;
    __syncthreads();
    for (int off = 128; off > 0; off >>= 1) {
        if (tid < off) red[tid] += red[tid + off];
        __syncthreads();
    }
    float inv = 1.f / red[0];
#pragma unroll
    for (int i = 0; i < 9; ++i) row[tid + 256 * i] = v[i] * inv;
}

__global__ __launch_bounds__(256) void attn_pv(const unsigned short* __restrict__ Hp2,
                                               const float* __restrict__ SG,
                                               float* __restrict__ PP) {
    int n = blockIdx.y;
    int sb = blockIdx.x;
    int tid = threadIdx.x;
    int d = tid & 127, half = tid >> 7;
    int s0 = sb * 128 + half * 64;
    float freq = expf(-(float)(d & ~1) * (9.210340371976184f / 128.f));
    bool odd = d & 1;
    const float* att = SG + (size_t)n * S2;
    float acc = 0.f;
    for (int i = 0; i < 64; ++i) {
        int s = s0 + i;
        float ang = (float)s * freq;
        float pe = odd ? cosf(ang) : sinf(ang);
        acc += att[s] * (b2f(Hp2[((size_t)n * S2 + s) * 128 + d]) + pe);
    }
    PP[((size_t)n * 18 + sb) * 256 + tid] = acc;
}

__global__ __launch_bounds__(128) void attn_pv_reduce(const float* __restrict__ PP,
                                                      float* __restrict__ out) {
    int n = blockIdx.x, d = threadIdx.x;
    float s = 0.f;
    for (int i = 0; i < 18; ++i) {
        const float* p = PP + ((size_t)n * 18 + i) * 256;
        s += p[d] + p[128 + d];
    }
    out[1024 + n * 128 + d] = s;
}

// --------------------------- launch ------------------------------------------

extern "C" void kernel_launch(void* const* d_in, const int* in_sizes, int n_in,
                              void* d_out, int out_size, void* d_ws, size_t ws_size,
                              hipStream_t stream) {
    const float* context = (const float*)d_in[0];
    const float* frame = (const float*)d_in[1];
    const float* Vw = (const float*)d_in[6];
    const float* Vb = (const float*)d_in[7];
    const float* Ow = (const float*)d_in[8];
    const float* Ob = (const float*)d_in[9];
    const float* gamma = (const float*)d_in[10];
    const float* beta = (const float*)d_in[11];
    const float* tpw = (const float*)d_in[12];
    const float* tpb = (const float*)d_in[13];
    const float* u1w = (const float*)d_in[14];
    const float* u1b = (const float*)d_in[15];
    const float* u2w = (const float*)d_in[16];
    const float* u2b = (const float*)d_in[17];
    float* ws = (float*)d_ws;
    float* out = (float*)d_out;

    unsigned short* XB = (unsigned short*)(ws + OFF_XB);
    unsigned short* YB = (unsigned short*)(ws + OFF_YB);
    unsigned short* VNB = (unsigned short*)(ws + OFF_VNB);
    unsigned short* WB1 = (unsigned short*)(ws + OFF_WB1);
    unsigned short* WB2 = (unsigned short*)(ws + OFF_WB2);
    float* ST = ws + OFF_ST;
    unsigned short* TWB = (unsigned short*)(ws + OFF_TWB);
    unsigned short* W1B = (unsigned short*)(ws + OFF_W1B);
    unsigned short* W2B = (unsigned short*)(ws + OFF_W2B);
    float* GP = ws + OFF_GP;
    float* R = ws + OFF_R;
    unsigned short* F0B = (unsigned short*)(ws + OFF_F0B);
    unsigned short* HP1B = (unsigned short*)(ws + OFF_HP1B);
    unsigned short* HP2B = (unsigned short*)(ws + OFF_HP2B);
    float* SG = ws + OFF_SG;
    float* PP = ws + OFF_PP;

    // all weight prep in one launch
    prep_weights<<<PW3 / 256, 256, 0, stream>>>(Vw, Ow, tpw, u1w, u2w,
                                                WB1, WB2, TWB, W1B, W2B);

    // context [8][6][1024][144] -> XB bf16 (pixel-major)
    transpose_cm_pm<<<dim3(HWP / 16, DIN / 64, B_ * TC), dim3(16, 16), 0, stream>>>(
        context, XB, DIN, HWP);

    for (int l = 0; l < 2; ++l) {
        // VN = relu(X*Vw^T + Vb)  [bf16]
        gemm_mfma<11, 0, 0><<<dim3(DFF / 128, P_CTX / 64, 1), 256, 0, stream>>>(
            XB, WB1 + (size_t)l * 524288, Vb + l * DFF, nullptr, VNB,
            P_CTX, DFF, DIN, 0, 0, 0, 0, 0, 0);
        // Y = X + relu(VN*Ow^T + Ob)  [bf16; resid = XB]
        gemm_mfma<15, 0, 0><<<dim3(DIN / 128, P_CTX / 64, 1), 256, 0, stream>>>(
            VNB, WB2 + (size_t)l * 524288, Ob + l * DIN, XB, YB,
            P_CTX, DIN, DFF, 0, 0, 0, 0, 0, 0);
        // BatchNorm (training-mode stats); XB <- BN(YB)
        zero_f32<<<8, 256, 0, stream>>>(ST, 2048);
        bn_stats_b<<<P_CTX / 64, 256, 0, stream>>>(YB, ST);
        bn_final<<<4, 256, 0, stream>>>(ST, gamma + l * DIN, beta + l * DIN);
        bn_apply_b<<<(P_CTX * DIN / 4) / 256, 256, 0, stream>>>(YB, XB, ST);
    }

    // temporal pool: split-K over 27 taps -> GP partials -> reduce
    gemm_mfma<0, 0, 1><<<dim3(1, NPOS / 64, 27), 256, 0, stream>>>(
        XB, TWB, nullptr, nullptr, GP, NPOS, DOUT, DIN,
        (size_t)DIN / 8 * DOUT * 8, (size_t)NPOS * DOUT, 0, 0, 0, 0);
    conv3_reduce<<<(NPOS * DOUT) / 256, 256, 0, stream>>>(GP, tpb, R);
    goal_reduce<<<8, 128, 0, stream>>>(R, out);

    // frame upsample path (bf16 throughout)
    transpose_cm_pm<<<dim3(HWP / 16, DIN / 64, NF), dim3(16, 16), 0, stream>>>(
        frame, F0B, DIN, HWP);
    // up1: relu(convT1), 4 quadrants via z, bf16 out with row remap
    gemm_mfma<11, 1, 0><<<dim3(DFF / 128, P_FRM / 64, 4), 256, 0, stream>>>(
        F0B, W1B, u1b, nullptr, HP1B, P_FRM, DFF, DIN,
        (size_t)DIN / 8 * DFF * 8, 0, 12, 144, 24, 576);
    // up2: convT2 (no relu), bf16 out with row remap -> HP2B
    gemm_mfma<9, 1, 0><<<dim3(DOUT / 128, P_H1 / 64, 4), 256, 0, stream>>>(
        HP1B, W2B, u2b, nullptr, HP2B, P_H1, DOUT, DFF,
        (size_t)DFF / 8 * DOUT * 8, 0, 24, 576, 48, 2304);

    // final goal/state attention
    attn_logits<<<dim3(S2 / 16, NF), 256, 0, stream>>>(HP2B, out, SG);
    attn_softmax<<<NF, 256, 0, stream>>>(SG);
    attn_pv<<<dim3(18, NF), 256, 0, stream>>>(HP2B, SG, PP);
    attn_pv_reduce<<<NF, 128, 0, stream>>>(PP, out);
}

// Round 9
// 336.255 us; speedup vs baseline: 1.1252x; 1.0755x over previous
//
#include <hip/hip_runtime.h>
#include <cstddef>
#include <cstdint>

// ---------------------------------------------------------------------------
// AttentionGoalState — round 9: 128x128 tiles restored (MTILE template),
// single-barrier 3-buffer K-loop pipeline (barrier -> stage t+2 -> counted
// vmcnt -> MFMA t).  All-bf16 chain, conv3 split-K partials kept.
//
// Simplifications (exact up to fp rounding):
//   attn = softmax(KQ); Vn = V * attn.sum(axis=2) == V  (rowsums == 1)
//   -> K/Q GEMMs + S^2 softmax skipped entirely.
//
// Pipeline correctness: top barrier of iter t ensures all waves finished
// iter t-1's ds_reads (pre-MFMA lgkmcnt(0) precedes the barrier in program
// order), so staging into buf[(t+2)%3] == buf[(t-1)%3] is race-free.  FIFO
// vmcnt(2L) leaves tiles t+1,t+2 in flight while guaranteeing tile t landed.
// A and B in LDS as [kg][slot][8]: fragment ds_read_b128 is 256B-contiguous
// across 16 lanes = conflict-free (verified R5: conflicts == 0).
// ---------------------------------------------------------------------------

static constexpr int B_ = 8, TC = 6, TF = 4, DIN = 1024, DFF = 512, DOUT = 128;
static constexpr int HWP = 144;
static constexpr int P_CTX = B_ * TC * HWP;      // 6912
static constexpr int NF = B_ * TF;               // 32
static constexpr int P_FRM = NF * HWP;           // 4608
static constexpr int P_H1 = NF * 24 * 24;        // 18432
static constexpr int P_H2 = NF * 48 * 48;        // 73728
static constexpr int S2 = 48 * 48;               // 2304
static constexpr int NPOS = 3200;                // 8*4*10*10 conv3d outputs

// ---- workspace offsets in FLOAT slots (peak ~97 MB) ----
static constexpr size_t OFF_XB   = 0;          // 3,538,944 slots (bf16 x2)
static constexpr size_t OFF_YB   = 3538944;
static constexpr size_t OFF_VNB  = 7077888;
static constexpr size_t OFF_WB1  = 8847360;
static constexpr size_t OFF_WB2  = 9371648;
static constexpr size_t OFF_ST   = 9895936;
static constexpr size_t OFF_TWB  = 9900032;
static constexpr size_t OFF_W1B  = 11669504;
static constexpr size_t OFF_W2B  = 12718080;
static constexpr size_t OFF_GP   = 12849152;   // 27*3200*128 f32
static constexpr size_t OFF_R    = 23908352;
static constexpr size_t OFF_F0B  = 0;          // phase C aliases
static constexpr size_t OFF_HP1B = 2359296;
static constexpr size_t OFF_HP2B = 7077888;
static constexpr size_t OFF_SG   = 12849152;   // aliases dead GP
static constexpr size_t OFF_PP   = 12922880;

typedef __attribute__((ext_vector_type(8))) short bf16x8;
typedef __attribute__((ext_vector_type(4))) float f32x4;
typedef __attribute__((ext_vector_type(4))) unsigned short us4;
typedef __attribute__((ext_vector_type(8))) unsigned short us8;

__device__ __forceinline__ unsigned short f2b(float f) {
    union { float f; uint32_t u; } x{f};
    uint32_t r = x.u + 0x7FFFu + ((x.u >> 16) & 1u);  // RNE
    return (unsigned short)(r >> 16);
}
__device__ __forceinline__ float b2f(unsigned short u) {
    union { uint32_t u; float f; } x;
    x.u = (uint32_t)u << 16;
    return x.f;
}

#define GL16(g, s)                                                        \
    __builtin_amdgcn_global_load_lds(                                     \
        (const __attribute__((address_space(1))) void*)(g),               \
        (__attribute__((address_space(3))) void*)(s), 16, 0, 0)

// --------------------------- helpers ---------------------------------------

// [F][C][HW] -> [F*HW][C] bf16 (tiled transpose, both sides coalesced)
__global__ __launch_bounds__(256) void transpose_cm_pm(const float* __restrict__ in,
                                                       unsigned short* __restrict__ outB,
                                                       int C, int HW) {
    __shared__ float T[64][17];
    int tx = threadIdx.x, ty = threadIdx.y;
    int f = blockIdx.z, hw0 = blockIdx.x * 16, c0 = blockIdx.y * 64;
#pragma unroll
    for (int i = 0; i < 4; ++i)
        T[ty + 16 * i][tx] = in[((size_t)f * C + c0 + ty + 16 * i) * HW + hw0 + tx];
    __syncthreads();
#pragma unroll
    for (int i = 0; i < 4; ++i)
        outB[((size_t)f * HW + hw0 + ty) * C + c0 + tx + 16 * i] = f2b(T[tx + 16 * i][ty]);
}

// ---- one-shot weight prep: all weights -> bf16 interleaved [K/8][N][8] ----
static constexpr int PW0 = 4 * 524288;             // Vw0,Ow0,Vw1,Ow1
static constexpr int PW1 = PW0 + 27 * 1024 * 128;  // + TWB
static constexpr int PW2 = PW1 + 4 * 512 * 1024;   // + W1B
static constexpr int PW3 = PW2 + 4 * 128 * 512;    // + W2B
__global__ __launch_bounds__(256) void prep_weights(
    const float* __restrict__ Vw, const float* __restrict__ Ow,
    const float* __restrict__ tp, const float* __restrict__ u1w,
    const float* __restrict__ u2w,
    unsigned short* __restrict__ WB1, unsigned short* __restrict__ WB2,
    unsigned short* __restrict__ TWB, unsigned short* __restrict__ W1B,
    unsigned short* __restrict__ W2B) {
    int t = blockIdx.x * 256 + threadIdx.x;
    if (t < PW0) {
        int which = t >> 19;        // 0:Vw0 1:Ow0 2:Vw1 3:Ow1
        int r = t & 524287;
        int kr = r & 7;
        int layer = which >> 1;
        if ((which & 1) == 0) {     // Vw: O=512, C=1024
            int o = (r >> 3) & 511, kg = (r >> 3) >> 9;
            WB1[(size_t)layer * 524288 + r] =
                f2b(Vw[(size_t)layer * 524288 + (size_t)o * 1024 + kg * 8 + kr]);
        } else {                    // Ow: O=1024, C=512
            int o = (r >> 3) & 1023, kg = (r >> 3) >> 10;
            WB2[(size_t)layer * 524288 + r] =
                f2b(Ow[(size_t)layer * 524288 + (size_t)o * 512 + kg * 8 + kr]);
        }
    } else if (t < PW1) {           // tp_w [128][1024][27] -> [tap][kg*128+o][8]
        int r = t - PW0;
        int kr = r & 7, o = (r >> 3) & 127, kg = (r >> 10) & 127, tap = r >> 17;
        int c = kg * 8 + kr;
        TWB[r] = f2b(tp[((size_t)o * 1024 + c) * 27 + tap]);
    } else if (t < PW2) {           // u1w [1024][512][2][2]: O=512, C=1024
        int r = t - PW1;
        int kr = r & 7, o = (r >> 3) % 512;
        int rest = (r >> 3) / 512;
        int kg = rest & 127, d = rest >> 7;
        W1B[r] = f2b(u1w[((size_t)(kg * 8 + kr) * 512 + o) * 4 + d]);
    } else if (t < PW3) {           // u2w [512][128][2][2]: O=128, C=512
        int r = t - PW2;
        int kr = r & 7, o = (r >> 3) & 127;
        int rest = (r >> 3) >> 7;
        int kg = rest & 63, d = rest >> 6;
        W2B[r] = f2b(u2w[((size_t)(kg * 8 + kr) * 128 + o) * 4 + d]);
    }
}

// --------------------------- MFMA GEMM (MT x 128 tile, 3-buf, 1 barrier) ----
// C[M,N] = epi(A[M,K] x B[K,N]).  A bf16 row-major (GATHER: im2col rows),
// B interleaved [K/8][N][8].
// EPI bits: 1=bias 2=relu 4=resid(bf16) 8=bf16out  (else f32 out + cStrideZ).
// blockIdx.z: tap (conv3d GATHER) or quadrant d (convT REMAP).
template <int EPI, int REMAP, int GATHER, int MT>
__global__ __launch_bounds__(256) void gemm_mfma(
    const unsigned short* __restrict__ A, const unsigned short* __restrict__ Bp,
    const float* __restrict__ bias, const unsigned short* __restrict__ resid,
    void* __restrict__ Cv, int M, int N, int K,
    size_t bStrideZ, size_t cStrideZ,
    int inW, int inHW, int outW, int outSPP) {
    constexpr int MI = MT / 32;   // m-frags per wave
    constexpr int AL = MT / 64;   // A staging loads per thread
    __shared__ unsigned short Al[3][MT * 32];   // [kg][row][8]
    __shared__ unsigned short Bl[3][128 * 32];  // [kg][n][8]
    __shared__ int sPix[MT];
    int tid = threadIdx.x;
    int w = tid >> 6, l = tid & 63;
    int m0 = blockIdx.y * MT, n0 = blockIdx.x * 128;
    int z = blockIdx.z;
    const unsigned short* Bpz = Bp + (size_t)z * bStrideZ;

    if (GATHER) {
        if (tid < MT) {
            int pos = m0 + tid;
            int ww = pos % 10;
            int r = pos / 10;
            int h = r % 10;
            r /= 10;
            int t = r & 3, b = r >> 2;
            int dt = z / 9, rr = z - dt * 9;
            int doff = dt * 144 + (rr / 3) * 12 + (rr % 3);
            sPix[tid] = ((b * 6 + t) * 12 + h) * 12 + ww + doff;
        }
        __syncthreads();
    }

    int wr = w >> 1, wc = w & 1;
    int l15 = l & 15, lg = l >> 4;

    // bias preload BEFORE staging so the vmcnt FIFO analysis in the loop holds
    float bv[4];
#pragma unroll
    for (int ni = 0; ni < 4; ++ni)
        bv[ni] = (EPI & 1) ? bias[n0 + wc * 64 + ni * 16 + l15] : 0.f;
    asm volatile("s_waitcnt vmcnt(0)" ::: "memory");

    // A staging: wave w = k-chunk w; lane l stages rows l (+64).
    const unsigned short* ag[AL];
    int aoff[AL];
#pragma unroll
    for (int a = 0; a < AL; ++a) {
        int row = l + a * 64;
        int grow = GATHER ? sPix[row] : (m0 + row);
        ag[a] = A + (size_t)grow * K + w * 8;
        aoff[a] = (w * MT + row) * 8;
    }
    // B staging: 2 GL16/thread; kg = (tid>>7) + 2c, n = tid&127
    int bkg = tid >> 7, bn = tid & 127;
    const unsigned short* bg0 = Bpz + ((size_t)bkg * N + n0 + bn) * 8;
    const unsigned short* bg1 = Bpz + ((size_t)(bkg + 2) * N + n0 + bn) * 8;
    const int boff0 = tid * 8, boff1 = (tid + 256) * 8;
    size_t bstep = (size_t)32 * N;

    f32x4 acc[MI][4];
#pragma unroll
    for (int mi = 0; mi < MI; ++mi)
#pragma unroll
        for (int ni = 0; ni < 4; ++ni) acc[mi][ni] = (f32x4){0.f, 0.f, 0.f, 0.f};

    int nt = K >> 5;  // >= 16 for all shapes here
    // prologue: stage buffers 0 and 1
#pragma unroll
    for (int a = 0; a < AL; ++a) { GL16(ag[a], &Al[0][aoff[a]]); ag[a] += 32; }
    GL16(bg0, &Bl[0][boff0]);
    GL16(bg1, &Bl[0][boff1]);
    bg0 += bstep; bg1 += bstep;
#pragma unroll
    for (int a = 0; a < AL; ++a) { GL16(ag[a], &Al[1][aoff[a]]); ag[a] += 32; }
    GL16(bg0, &Bl[1][boff0]);
    GL16(bg1, &Bl[1][boff1]);
    bg0 += bstep; bg1 += bstep;

    int bc = 0, sb = 2;
    for (int t = 0; t < nt; ++t) {
        __builtin_amdgcn_s_barrier();   // all waves done reading buf[sb]
        if (t + 2 < nt) {
#pragma unroll
            for (int a = 0; a < AL; ++a) { GL16(ag[a], &Al[sb][aoff[a]]); ag[a] += 32; }
            GL16(bg0, &Bl[sb][boff0]);
            GL16(bg1, &Bl[sb][boff1]);
            bg0 += bstep; bg1 += bstep;
            if (MT == 128)
                asm volatile("s_waitcnt vmcnt(8)" ::: "memory");
            else
                asm volatile("s_waitcnt vmcnt(6)" ::: "memory");
        } else if (t + 2 == nt) {
            if (MT == 128)
                asm volatile("s_waitcnt vmcnt(4)" ::: "memory");
            else
                asm volatile("s_waitcnt vmcnt(3)" ::: "memory");
        } else {
            asm volatile("s_waitcnt vmcnt(0)" ::: "memory");
        }
        __builtin_amdgcn_sched_barrier(0);
        bf16x8 af[MI], bf[4];
#pragma unroll
        for (int mi = 0; mi < MI; ++mi)
            af[mi] = *(const bf16x8*)&Al[bc][(lg * MT + wr * (MT / 2) + mi * 16 + l15) * 8];
#pragma unroll
        for (int ni = 0; ni < 4; ++ni)
            bf[ni] = *(const bf16x8*)&Bl[bc][(lg * 128 + wc * 64 + ni * 16 + l15) * 8];
#pragma unroll
        for (int mi = 0; mi < MI; ++mi)
#pragma unroll
            for (int ni = 0; ni < 4; ++ni)
                acc[mi][ni] = __builtin_amdgcn_mfma_f32_16x16x32_bf16(
                    af[mi], bf[ni], acc[mi][ni], 0, 0, 0);
        __builtin_amdgcn_sched_barrier(0);
        bc = (bc == 2) ? 0 : bc + 1;
        sb = (sb == 2) ? 0 : sb + 1;
    }

    // epilogue
    float* Cf = (float*)Cv + (size_t)z * cStrideZ;
    unsigned short* Cb = (unsigned short*)Cv;
#pragma unroll
    for (int mi = 0; mi < MI; ++mi) {
#pragma unroll
        for (int r = 0; r < 4; ++r) {
            int m = m0 + wr * (MT / 2) + mi * 16 + lg * 4 + r;
            int orow = m;
            if (REMAP) {
                int ni_ = m / inHW;
                int rem = m - ni_ * inHW;
                int h = rem / inW, ww = rem - h * inW;
                orow = ni_ * outSPP + (2 * h + (z >> 1)) * outW + (2 * ww + (z & 1));
            }
#pragma unroll
            for (int ni = 0; ni < 4; ++ni) {
                int n = n0 + wc * 64 + ni * 16 + l15;
                float v = acc[mi][ni][r] + bv[ni];
                if (EPI & 2) v = fmaxf(v, 0.f);
                if (EPI & 4) v += b2f(resid[(size_t)m * N + n]);
                if (EPI & 8)
                    Cb[(size_t)orow * N + n] = f2b(v);
                else
                    Cf[(size_t)orow * N + n] = v;
            }
        }
    }
}

// --------------------------- conv3d tail -------------------------------------

__global__ __launch_bounds__(256) void conv3_reduce(const float* __restrict__ Gp,
                                                    const float* __restrict__ bias,
                                                    float* __restrict__ R) {
    int idx = blockIdx.x * 256 + threadIdx.x;  // 3200*128
    float s = 0.f;
    for (int tap = 0; tap < 27; ++tap) s += Gp[(size_t)tap * (NPOS * 128) + idx];
    R[idx] = fmaxf(s + bias[idx & 127], 0.f);
}

__global__ __launch_bounds__(128) void goal_reduce(const float* __restrict__ R,
                                                   float* __restrict__ out) {
    int b = blockIdx.x, o = threadIdx.x;
    float s = 0.f;
    for (int i = 0; i < 400; ++i) s += R[(size_t)(b * 400 + i) * 128 + o];
    out[b * 128 + o] = s * (1.f / 400.f);
}

// --------------------------- BatchNorm (bf16 in) -----------------------------

__global__ __launch_bounds__(256) void bn_stats_b(const unsigned short* __restrict__ YB,
                                                  float* __restrict__ st) {
    int tid = threadIdx.x;
    int p0 = blockIdx.x * 64;
    int c0 = tid * 4;
    float s[4] = {0, 0, 0, 0}, q[4] = {0, 0, 0, 0};
    for (int pp = 0; pp < 64; ++pp) {
        us4 y = *(const us4*)(YB + (size_t)(p0 + pp) * 1024 + c0);
#pragma unroll
        for (int j = 0; j < 4; ++j) {
            float v = b2f(y[j]);
            s[j] += v;
            q[j] += v * v;
        }
    }
#pragma unroll
    for (int j = 0; j < 4; ++j) {
        atomicAdd(&st[c0 + j], s[j]);
        atomicAdd(&st[1024 + c0 + j], q[j]);
    }
}

__global__ __launch_bounds__(256) void bn_final(float* __restrict__ st,
                                                const float* __restrict__ gamma,
                                                const float* __restrict__ beta) {
    int c = blockIdx.x * 256 + threadIdx.x;
    if (c >= 1024) return;
    const float invn = 1.f / 6912.f;
    float mean = st[c] * invn;
    float var = st[1024 + c] * invn - mean * mean;
    float sc = gamma[c] * rsqrtf(var + 1e-5f);
    st[2048 + c] = sc;
    st[3072 + c] = beta[c] - mean * sc;
}

// XB = scale*YB + shift  (bf16 -> bf16)
__global__ __launch_bounds__(256) void bn_apply_b(const unsigned short* __restrict__ YB,
                                                  unsigned short* __restrict__ XB,
                                                  const float* __restrict__ st) {
    const float* scale = st + 2048;
    const float* shift = st + 3072;
    int idx = blockIdx.x * 256 + threadIdx.x;  // over P_CTX*1024/4
    int c0 = (idx & 255) << 2;
    us4 y = ((const us4*)YB)[idx];
    us4 o;
#pragma unroll
    for (int j = 0; j < 4; ++j) o[j] = f2b(b2f(y[j]) * scale[c0 + j] + shift[c0 + j]);
    ((us4*)XB)[idx] = o;
}

// --------------------------- final goal/state attention ----------------------

__global__ __launch_bounds__(256) void attn_logits(const unsigned short* __restrict__ Hp2,
                                                   const float* __restrict__ out,
                                                   float* __restrict__ SG) {
    int n = blockIdx.y;
    int tid = threadIdx.x;
    int s = blockIdx.x * 16 + (tid >> 4);
    int l16 = tid & 15;
    us8 row = *((const us8*)(Hp2 + ((size_t)n * S2 + s) * 128) + l16);
    const float* g = out + (n & 7) * 128 + l16 * 8;
    float dot = 0.f;
#pragma unroll
    for (int i = 0; i < 8; ++i) dot += b2f(row[i]) * g[i];
    dot += __shfl_xor(dot, 1);
    dot += __shfl_xor(dot, 2);
    dot += __shfl_xor(dot, 4);
    dot += __shfl_xor(dot, 8);
    if (l16 == 0) SG[(size_t)n * S2 + s] = dot * 0.0883883476483184f;
}

__global__ __launch_bounds__(256) void attn_softmax(float* __restrict__ SG) {
    __shared__ float red[256];
    int n = blockIdx.x, tid = threadIdx.x;
    float* row = SG + (size_t)n * S2;
    float v[9];
    float lmax = -3.4e38f;
#pragma unroll
    for (int i = 0; i < 9; ++i) {
        v[i] = row[tid + 256 * i];
        lmax = fmaxf(lmax, v[i]);
    }
    red[tid] = lmax;
    __syncthreads();
    for (int off = 128; off > 0; off >>= 1) {
        if (tid < off) red[tid] = fmaxf(red[tid], red[tid + off]);
        __syncthreads();
    }
    float m = red[0];
    __syncthreads();
    float ls = 0.f;
#pragma unroll
    for (int i = 0; i < 9; ++i) {
        v[i] = expf(v[i] - m);
        ls += v[i];
    }
    red[tid] = ls;
    __syncthreads();
    for (int off = 128; off > 0; off >>= 1) {
        if (tid < off) red[tid] += red[tid + off];
        __syncthreads();
    }
    float inv = 1.f / red[0];
#pragma unroll
    for (int i = 0; i < 9; ++i) row[tid + 256 * i] = v[i] * inv;
}

__global__ __launch_bounds__(256) void attn_pv(const unsigned short* __restrict__ Hp2,
                                               const float* __restrict__ SG,
                                               float* __restrict__ PP) {
    int n = blockIdx.y;
    int sb = blockIdx.x;
    int tid = threadIdx.x;
    int d = tid & 127, half = tid >> 7;
    int s0 = sb * 128 + half * 64;
    float freq = expf(-(float)(d & ~1) * (9.210340371976184f / 128.f));
    bool odd = d & 1;
    const float* att = SG + (size_t)n * S2;
    float acc = 0.f;
    for (int i = 0; i < 64; ++i) {
        int s = s0 + i;
        float ang = (float)s * freq;
        float pe = odd ? cosf(ang) : sinf(ang);
        acc += att[s] * (b2f(Hp2[((size_t)n * S2 + s) * 128 + d]) + pe);
    }
    PP[((size_t)n * 18 + sb) * 256 + tid] = acc;
}

__global__ __launch_bounds__(128) void attn_pv_reduce(const float* __restrict__ PP,
                                                      float* __restrict__ out) {
    int n = blockIdx.x, d = threadIdx.x;
    float s = 0.f;
    for (int i = 0; i < 18; ++i) {
        const float* p = PP + ((size_t)n * 18 + i) * 256;
        s += p[d] + p[128 + d];
    }
    out[1024 + n * 128 + d] = s;
}

// --------------------------- launch ------------------------------------------

extern "C" void kernel_launch(void* const* d_in, const int* in_sizes, int n_in,
                              void* d_out, int out_size, void* d_ws, size_t ws_size,
                              hipStream_t stream) {
    const float* context = (const float*)d_in[0];
    const float* frame = (const float*)d_in[1];
    const float* Vw = (const float*)d_in[6];
    const float* Vb = (const float*)d_in[7];
    const float* Ow = (const float*)d_in[8];
    const float* Ob = (const float*)d_in[9];
    const float* gamma = (const float*)d_in[10];
    const float* beta = (const float*)d_in[11];
    const float* tpw = (const float*)d_in[12];
    const float* tpb = (const float*)d_in[13];
    const float* u1w = (const float*)d_in[14];
    const float* u1b = (const float*)d_in[15];
    const float* u2w = (const float*)d_in[16];
    const float* u2b = (const float*)d_in[17];
    float* ws = (float*)d_ws;
    float* out = (float*)d_out;

    unsigned short* XB = (unsigned short*)(ws + OFF_XB);
    unsigned short* YB = (unsigned short*)(ws + OFF_YB);
    unsigned short* VNB = (unsigned short*)(ws + OFF_VNB);
    unsigned short* WB1 = (unsigned short*)(ws + OFF_WB1);
    unsigned short* WB2 = (unsigned short*)(ws + OFF_WB2);
    float* ST = ws + OFF_ST;
    unsigned short* TWB = (unsigned short*)(ws + OFF_TWB);
    unsigned short* W1B = (unsigned short*)(ws + OFF_W1B);
    unsigned short* W2B = (unsigned short*)(ws + OFF_W2B);
    float* GP = ws + OFF_GP;
    float* R = ws + OFF_R;
    unsigned short* F0B = (unsigned short*)(ws + OFF_F0B);
    unsigned short* HP1B = (unsigned short*)(ws + OFF_HP1B);
    unsigned short* HP2B = (unsigned short*)(ws + OFF_HP2B);
    float* SG = ws + OFF_SG;
    float* PP = ws + OFF_PP;

    // all weight prep in one launch
    prep_weights<<<PW3 / 256, 256, 0, stream>>>(Vw, Ow, tpw, u1w, u2w,
                                                WB1, WB2, TWB, W1B, W2B);

    // context [8][6][1024][144] -> XB bf16 (pixel-major)
    transpose_cm_pm<<<dim3(HWP / 16, DIN / 64, B_ * TC), dim3(16, 16), 0, stream>>>(
        context, XB, DIN, HWP);

    for (int l = 0; l < 2; ++l) {
        // VN = relu(X*Vw^T + Vb)  [bf16]  (64-tile: 432 blocks)
        gemm_mfma<11, 0, 0, 64><<<dim3(DFF / 128, P_CTX / 64, 1), 256, 0, stream>>>(
            XB, WB1 + (size_t)l * 524288, Vb + l * DFF, nullptr, VNB,
            P_CTX, DFF, DIN, 0, 0, 0, 0, 0, 0);
        // Y = X + relu(VN*Ow^T + Ob)  [bf16; resid = XB]  (128-tile: 432 blocks)
        gemm_mfma<15, 0, 0, 128><<<dim3(DIN / 128, P_CTX / 128, 1), 256, 0, stream>>>(
            VNB, WB2 + (size_t)l * 524288, Ob + l * DIN, XB, YB,
            P_CTX, DIN, DFF, 0, 0, 0, 0, 0, 0);
        // BatchNorm (training-mode stats); XB <- BN(YB)
        hipMemsetAsync(ST, 0, 2048 * sizeof(float), stream);
        bn_stats_b<<<P_CTX / 64, 256, 0, stream>>>(YB, ST);
        bn_final<<<4, 256, 0, stream>>>(ST, gamma + l * DIN, beta + l * DIN);
        bn_apply_b<<<(P_CTX * DIN / 4) / 256, 256, 0, stream>>>(YB, XB, ST);
    }

    // temporal pool: split-K over 27 taps -> GP partials -> reduce (675 blocks)
    gemm_mfma<0, 0, 1, 128><<<dim3(1, NPOS / 128, 27), 256, 0, stream>>>(
        XB, TWB, nullptr, nullptr, GP, NPOS, DOUT, DIN,
        (size_t)DIN / 8 * DOUT * 8, (size_t)NPOS * DOUT, 0, 0, 0, 0);
    conv3_reduce<<<(NPOS * DOUT) / 256, 256, 0, stream>>>(GP, tpb, R);
    goal_reduce<<<8, 128, 0, stream>>>(R, out);

    // frame upsample path (bf16 throughout)
    transpose_cm_pm<<<dim3(HWP / 16, DIN / 64, NF), dim3(16, 16), 0, stream>>>(
        frame, F0B, DIN, HWP);
    // up1: relu(convT1), 4 quadrants via z, bf16 out with row remap (576 blocks)
    gemm_mfma<11, 1, 0, 128><<<dim3(DFF / 128, P_FRM / 128, 4), 256, 0, stream>>>(
        F0B, W1B, u1b, nullptr, HP1B, P_FRM, DFF, DIN,
        (size_t)DIN / 8 * DFF * 8, 0, 12, 144, 24, 576);
    // up2: convT2 (no relu), bf16 out with row remap -> HP2B (576 blocks)
    gemm_mfma<9, 1, 0, 128><<<dim3(DOUT / 128, P_H1 / 128, 4), 256, 0, stream>>>(
        HP1B, W2B, u2b, nullptr, HP2B, P_H1, DOUT, DFF,
        (size_t)DFF / 8 * DOUT * 8, 0, 24, 576, 48, 2304);

    // final goal/state attention
    attn_logits<<<dim3(S2 / 16, NF), 256, 0, stream>>>(HP2B, out, SG);
    attn_softmax<<<NF, 256, 0, stream>>>(SG);
    attn_pv<<<dim3(18, NF), 256, 0, stream>>>(HP2B, SG, PP);
    attn_pv_reduce<<<NF, 128, 0, stream>>>(PP, out);
}